// Round 13
// baseline (233.451 us; speedup 1.0000x reference)
//
#include <hip/hip_runtime.h>
#include <hip/hip_fp16.h>

// QuantizedLinearWhisper: E2M1 block-32 fake-quant of x and W, then x_q @ W_q^T + bias.
// M=12000 (pad 12032=47*256), K=1280, N=5120. Outputs: out[12000][5120] f32, scale_w[5120][40] f32.
//
// R13 = R11 chassis + CORRECT lag-1 reads (R12 fixed). Retirement-based WAR ledger:
// a staged region requires all its reads RETIRED (first MFMA consumption forces the
// lgkm wait) one barrier earlier. wr=0 waves read A rows 0..127 as BOTH aLO and aHI,
// so A is stageable only at Phi4 (aHI retires Q3/Phi3); B stageable at Phi3.
// Reads: Phi1 bHI(t), Phi2 aHI(t), Phi3 aLO(t+1), Phi4 bLO(t+1) [ping-pong].
// Stages: Phi3 B(t+2) [4 glds], Phi4 A(t+2) [4 glds].
// Publish: vmcnt(0) at Phi2 end (outstanding = t+1 glds issued ~3 phases prior -> free).
// Quadrants: Q1(aLO*bLO) Q2(aLO*bHI) Q3(aHI*bHI) Q4(aHI*bLO). 4 barriers/tile.

typedef _Float16 f16;
typedef _Float16 f16x8 __attribute__((ext_vector_type(8)));
typedef float f32x4 __attribute__((ext_vector_type(4)));

#define M_ROWS 12000
#define M_PAD  12032
#define N_COLS 5120
#define K_DIM  1280
#define KB     40
#define NTN    20          // N tiles of 256

#define BAR()   asm volatile("s_barrier" ::: "memory")
#define VMCNT(N) asm volatile("s_waitcnt vmcnt(%0)" :: "i"(N) : "memory")
#define GLDS(gp, lp) __builtin_amdgcn_global_load_lds( \
    (const __attribute__((address_space(1))) unsigned*)(gp), \
    (__attribute__((address_space(3))) unsigned*)(lp), 16, 0, 0)

// ---- E2M1 nearest-level (strict > boundaries, identical to reference) ----
__device__ __forceinline__ float e2m1_level(float a) {
    float lv;
    if (a > 2.5f)       lv = (a > 3.5f) ? ((a > 5.0f) ? 6.0f : 4.0f) : 3.0f;
    else if (a > 1.25f) lv = (a > 1.75f) ? 2.0f : 1.5f;
    else                lv = (a > 0.75f) ? 1.0f : ((a > 0.25f) ? 0.5f : 0.0f);
    return lv;
}

__global__ __launch_bounds__(256) void quant_x_kernel(const float* __restrict__ x,
                                                      f16* __restrict__ xq) {
    int t = blockIdx.x * blockDim.x + threadIdx.x;
    int row = t / 160;
    int c8  = t % 160;
    f16x8 o;
    if (row < M_ROWS) {
        const float* p = x + (size_t)row * K_DIM + c8 * 8;
        float v[8];
        *(float4*)&v[0] = *(const float4*)p;
        *(float4*)&v[4] = *(const float4*)(p + 4);
        float am = 0.0f;
        #pragma unroll
        for (int i = 0; i < 8; ++i) am = fmaxf(am, fabsf(v[i]));
        am = fmaxf(am, __shfl_xor(am, 1));
        am = fmaxf(am, __shfl_xor(am, 2));
        float scale = fmaxf(am / 6.0f, 1e-12f);
        #pragma unroll
        for (int i = 0; i < 8; ++i) {
            float tq = v[i] / scale;
            float q  = copysignf(e2m1_level(fabsf(tq)), tq) * scale;
            o[i] = (f16)q;
        }
    } else {
        #pragma unroll
        for (int i = 0; i < 8; ++i) o[i] = (f16)0.0f;
    }
    *(f16x8*)(xq + (size_t)row * K_DIM + c8 * 8) = o;
}

__global__ __launch_bounds__(256) void quant_w_kernel(const float* __restrict__ w,
                                                      f16* __restrict__ wq,
                                                      float* __restrict__ scale_out) {
    int t = blockIdx.x * blockDim.x + threadIdx.x;
    int row = t / 160;
    int c8  = t % 160;
    const float* p = w + (size_t)row * K_DIM + c8 * 8;
    float v[8];
    *(float4*)&v[0] = *(const float4*)p;
    *(float4*)&v[4] = *(const float4*)(p + 4);
    float am = 0.0f;
    #pragma unroll
    for (int i = 0; i < 8; ++i) am = fmaxf(am, fabsf(v[i]));
    am = fmaxf(am, __shfl_xor(am, 1));
    am = fmaxf(am, __shfl_xor(am, 2));
    float scale = fmaxf(am / 6.0f, 1e-12f);
    if ((t & 3) == 0) scale_out[row * KB + (c8 >> 2)] = scale;
    f16x8 o;
    #pragma unroll
    for (int i = 0; i < 8; ++i) {
        float tq = v[i] / scale;
        float q  = copysignf(e2m1_level(fabsf(tq)), tq) * scale;
        o[i] = (f16)q;
    }
    *(f16x8*)(wq + (size_t)row * K_DIM + c8 * 8) = o;
}

// ---- GEMM 256x256, BK=64, 8 waves 2x4, per-wave 128x64 out ----
// LDS per tile-buffer: A [256 rows][8 chunks of 16B] (32KB) + B same; chunk c of row r
// at slot (c ^ (r&7)); stage pre-swizzles the global source chunk. 128 KiB total.

__device__ __forceinline__ void stage_half(const f16* __restrict__ g, f16* l, int tid) {
    #pragma unroll
    for (int s = 0; s < 2; ++s) {
        int j = s * 512 + tid;          // chunk 0..1023 (128 rows x 8 chunks)
        int r = j >> 3;
        int c = (j & 7) ^ (r & 7);
        GLDS(g + (size_t)r * K_DIM + c * 8, l + (size_t)j * 8);
    }
}

#define READ_A(dst, buf, rbase)                                                \
    _Pragma("unroll")                                                          \
    for (int fm = 0; fm < 4; ++fm) {                                           \
        dst[fm][0] = *(const f16x8*)&(buf)[((rbase) + fm * 16) * 64 + swz[0]]; \
        dst[fm][1] = *(const f16x8*)&(buf)[((rbase) + fm * 16) * 64 + swz[1]]; \
    }
#define READ_B(dst, buf, rbase)                                                \
    _Pragma("unroll")                                                          \
    for (int fn = 0; fn < 2; ++fn) {                                           \
        dst[fn][0] = *(const f16x8*)&(buf)[((rbase) + fn * 16) * 64 + swz[0]]; \
        dst[fn][1] = *(const f16x8*)&(buf)[((rbase) + fn * 16) * 64 + swz[1]]; \
    }
#define MFMA_Q(ma, mb, mo, no)                                                 \
    __builtin_amdgcn_s_setprio(1);                                             \
    _Pragma("unroll")                                                          \
    for (int fm = 0; fm < 4; ++fm)                                             \
        _Pragma("unroll")                                                      \
        for (int fn = 0; fn < 2; ++fn) {                                       \
            acc[fm + mo][fn + no] = __builtin_amdgcn_mfma_f32_16x16x32_f16(    \
                ma[fm][0], mb[fn][0], acc[fm + mo][fn + no], 0, 0, 0);         \
            acc[fm + mo][fn + no] = __builtin_amdgcn_mfma_f32_16x16x32_f16(    \
                ma[fm][1], mb[fn][1], acc[fm + mo][fn + no], 0, 0, 0);         \
        }                                                                      \
    __builtin_amdgcn_s_setprio(0);

// One K64-tile, lag-1. X = buf[PAR] (tile t, restage target t+2), Y = other (t+1).
// aLO and bLO[PAR] preloaded (read at Phi3/Phi4 of tile t-1).
template<int PAR, bool STAGE, bool VM, bool READNEXT>
__device__ __forceinline__ void ktile(f16* Xa, f16* Xb,
                                      const f16* Ya, const f16* Yb,
                                      const f16* gA2, const f16* gB2,
                                      f16x8 (&aLO)[4][2], f16x8 (&bLO)[2][2][2],
                                      f32x4 (&acc)[8][4],
                                      int tid, int arow0, int brow0, const int (&swz)[2]) {
    f16x8 bHI[2][2], aHI[4][2];

    // ---- Phi1: read bHI(t) [consumed Phi2]; Q1 = aLO*bLO.
    //      Retires aLO(t) and bLO(t) reads (Q1 consumes them).
    READ_B(bHI, Xb, brow0 + 32);
    MFMA_Q(aLO, bLO[PAR], 0, 0);
    BAR();

    // ---- Phi2: read aHI(t) [consumed Phi3]; Q2 = aLO*bHI (retires bHI reads);
    //      publish tile t+1: vmcnt(0) drains its 8 glds (issued >=3 phases ago).
    READ_A(aHI, Xa, arow0 + 64);
    MFMA_Q(aLO, bHI, 0, 2);
    if (VM) VMCNT(0);
    BAR();

    // ---- Phi3: stage B(t+2) -> Xb (bLO retired Phi1, bHI retired Phi2, +barriers);
    //      read aLO(t+1) from Ya [published Phi2]; Q3 = aHI*bHI (retires aHI reads).
    if (STAGE) { stage_half(gB2, Xb, tid); stage_half(gB2 + 128 * K_DIM, Xb + 8192, tid); }
    if (READNEXT) { READ_A(aLO, Ya, arow0); }
    MFMA_Q(aHI, bHI, 4, 2);
    BAR();

    // ---- Phi4: stage A(t+2) -> Xa (aLO retired Phi1, aHI retired Phi3, +barriers);
    //      read bLO(t+1) into other parity set; Q4 = aHI*bLO[PAR].
    if (STAGE) { stage_half(gA2, Xa, tid); stage_half(gA2 + 128 * K_DIM, Xa + 8192, tid); }
    if (READNEXT) { READ_B(bLO[1 - PAR], Yb, brow0); }
    MFMA_Q(aHI, bLO[PAR], 4, 0);
    BAR();
}

__global__ __launch_bounds__(512, 2) void gemm_kernel(const f16* __restrict__ A,
                                                      const f16* __restrict__ B,
                                                      const float* __restrict__ bias,
                                                      float* __restrict__ C) {
    extern __shared__ f16 sm[];            // 2 tile-bufs x (A 16384 + B 16384 f16) = 128 KiB
    int mt = blockIdx.x / NTN;
    int nt = blockIdx.x % NTN;

    int tid  = threadIdx.x;
    int lane = tid & 63;
    int wid  = tid >> 6;
    int wr   = wid >> 2;                   // 0..1
    int wc   = wid & 3;                    // 0..3
    int l15  = lane & 15;

    int swz[2] = { (((lane >> 4)    ) ^ (lane & 7)) * 8,
                   (((lane >> 4) + 4) ^ (lane & 7)) * 8 };
    int arow0 = wr * 128 + l15;
    int brow0 = wc * 64 + l15;

    const f16* gAb = A + (size_t)(mt * 256) * K_DIM;
    const f16* gBb = B + (size_t)(nt * 256) * K_DIM;

    f16* A0 = sm;
    f16* B0 = sm + 16384;
    f16* A1 = sm + 32768;
    f16* B1 = sm + 49152;

    f32x4 acc[8][4] = {};
    f16x8 aLO[4][2];
    f16x8 bLO[2][2][2];

    // prologue: stage tiles 0 and 1 fully; vmcnt(8) publishes tile0 (tile1's 8 in
    // flight, drained by Phi2(0)'s vmcnt(0)); read tile0's aLO + bLO[0].
    stage_half(gAb,               A0,        tid);
    stage_half(gAb + 128 * K_DIM, A0 + 8192, tid);
    stage_half(gBb,               B0,        tid);
    stage_half(gBb + 128 * K_DIM, B0 + 8192, tid);
    stage_half(gAb + 64,               A1,        tid);
    stage_half(gAb + 64 + 128 * K_DIM, A1 + 8192, tid);
    stage_half(gBb + 64,               B1,        tid);
    stage_half(gBb + 64 + 128 * K_DIM, B1 + 8192, tid);
    VMCNT(8);
    BAR();
    READ_A(aLO, A0, arow0);
    READ_B(bLO[0], B0, brow0);

    // main loop: tiles 0..17 staged; t=18 (no stage, still publishes t=19 + lag-reads);
    // t=19 (nothing extra).
    for (int tt = 0; tt < 9; ++tt) {
        int t = 2 * tt;
        ktile<0, true, true, true>(A0, B0, A1, B1,
                                   gAb + (t + 2) * 64, gBb + (t + 2) * 64,
                                   aLO, bLO, acc, tid, arow0, brow0, swz);
        ktile<1, true, true, true>(A1, B1, A0, B0,
                                   gAb + (t + 3) * 64, gBb + (t + 3) * 64,
                                   aLO, bLO, acc, tid, arow0, brow0, swz);
    }
    ktile<0, false, true, true>(A0, B0, A1, B1, gAb, gBb,
                                aLO, bLO, acc, tid, arow0, brow0, swz);   // t=18
    ktile<1, false, false, false>(A1, B1, A0, B0, gAb, gBb,
                                  aLO, bLO, acc, tid, arow0, brow0, swz); // t=19

    // ---- epilogue: C = acc + bias.  C/D layout: col=lane&15, row=(lane>>4)*4+j
    int crow0 = mt * 256 + wr * 128;
    int ccol  = nt * 256 + wc * 64 + l15;
    float bz[4];
    #pragma unroll
    for (int fn = 0; fn < 4; ++fn) bz[fn] = bias[ccol + fn * 16];

    #pragma unroll
    for (int fm = 0; fm < 8; ++fm) {
        #pragma unroll
        for (int j = 0; j < 4; ++j) {
            int row = crow0 + fm * 16 + (lane >> 4) * 4 + j;
            if (row < M_ROWS) {
                float* cp = C + (size_t)row * N_COLS + ccol;
                #pragma unroll
                for (int fn = 0; fn < 4; ++fn)
                    cp[fn * 16] = acc[fm][fn][j] + bz[fn];
            }
        }
    }
}

extern "C" void kernel_launch(void* const* d_in, const int* in_sizes, int n_in,
                              void* d_out, int out_size, void* d_ws, size_t ws_size,
                              hipStream_t stream) {
    const float* x      = (const float*)d_in[0];
    const float* weight = (const float*)d_in[1];
    const float* bias   = (const float*)d_in[2];
    float* out     = (float*)d_out;
    float* scale_w = (float*)d_out + (size_t)M_ROWS * N_COLS;

    f16* xq = (f16*)d_ws;
    f16* wq = (f16*)((char*)d_ws + (size_t)M_PAD * K_DIM * sizeof(f16));

    (void)hipFuncSetAttribute((const void*)gemm_kernel,
                              hipFuncAttributeMaxDynamicSharedMemorySize, 131072);

    {
        int threads = M_PAD * (K_DIM / 8);
        quant_x_kernel<<<threads / 256, 256, 0, stream>>>(x, xq);
    }
    {
        int threads = N_COLS * (K_DIM / 8);
        quant_w_kernel<<<threads / 256, 256, 0, stream>>>(weight, wq, scale_w);
    }
    {
        int grid = (M_PAD / 256) * (N_COLS / 256);   // 47 * 20 = 940
        gemm_kernel<<<grid, 512, 131072, stream>>>(xq, wq, bias, out);
    }
}

// Round 14
// 194.956 us; speedup vs baseline: 1.1975x; 1.1975x over previous
//
#include <hip/hip_runtime.h>
#include <hip/hip_fp16.h>

// QuantizedLinearWhisper: E2M1 block-32 fake-quant of x and W, then x_q @ W_q^T + bias.
// M=12000 (pad 12032=47*256), K=1280, N=5120. Outputs: out[12000][5120] f32, scale_w[5120][40] f32.
//
// R14: lag-1 schedule with peak-80 fragment liveness (no ping-pong sets, aHI k-split).
// 256x256, BK=64, 8 waves 2x4, 1 block/CU. Quadrants Q1(aLO*bLO) Q2(aLO*bHI)
// Q3(aHI*bHI, k0-then-k1) Q4(aHI*bLO). Reads: Phi1 bLO+bHI(8), Phi2 aHI.k0(4),
// Phi3 aHI.k1(4), Phi4 aLO(t+1)(8). Stages: Phi3 B(t+2), Phi4 A(t+2).
// Barriers: Phi2-end; Phi3-end with vmcnt(4) publish (queue B(t+1),A(t+1),B(t+2)).
// Phi4 -> next Phi1 flows with no barrier. XOR swizzle (0 conflicts), setprio on MFMA.

typedef _Float16 f16;
typedef _Float16 f16x8 __attribute__((ext_vector_type(8)));
typedef float f32x4 __attribute__((ext_vector_type(4)));

#define M_ROWS 12000
#define M_PAD  12032
#define N_COLS 5120
#define K_DIM  1280
#define KB     40
#define NTN    20          // N tiles of 256

#define BAR()   asm volatile("s_barrier" ::: "memory")
#define VMCNT(N) asm volatile("s_waitcnt vmcnt(%0)" :: "i"(N) : "memory")
#define GLDS(gp, lp) __builtin_amdgcn_global_load_lds( \
    (const __attribute__((address_space(1))) unsigned*)(gp), \
    (__attribute__((address_space(3))) unsigned*)(lp), 16, 0, 0)

// ---- E2M1 nearest-level (strict > boundaries, identical to reference) ----
__device__ __forceinline__ float e2m1_level(float a) {
    float lv;
    if (a > 2.5f)       lv = (a > 3.5f) ? ((a > 5.0f) ? 6.0f : 4.0f) : 3.0f;
    else if (a > 1.25f) lv = (a > 1.75f) ? 2.0f : 1.5f;
    else                lv = (a > 0.75f) ? 1.0f : ((a > 0.25f) ? 0.5f : 0.0f);
    return lv;
}

__global__ __launch_bounds__(256) void quant_x_kernel(const float* __restrict__ x,
                                                      f16* __restrict__ xq) {
    int t = blockIdx.x * blockDim.x + threadIdx.x;
    int row = t / 160;
    int c8  = t % 160;
    f16x8 o;
    if (row < M_ROWS) {
        const float* p = x + (size_t)row * K_DIM + c8 * 8;
        float v[8];
        *(float4*)&v[0] = *(const float4*)p;
        *(float4*)&v[4] = *(const float4*)(p + 4);
        float am = 0.0f;
        #pragma unroll
        for (int i = 0; i < 8; ++i) am = fmaxf(am, fabsf(v[i]));
        am = fmaxf(am, __shfl_xor(am, 1));
        am = fmaxf(am, __shfl_xor(am, 2));
        float scale = fmaxf(am / 6.0f, 1e-12f);
        #pragma unroll
        for (int i = 0; i < 8; ++i) {
            float tq = v[i] / scale;
            float q  = copysignf(e2m1_level(fabsf(tq)), tq) * scale;
            o[i] = (f16)q;
        }
    } else {
        #pragma unroll
        for (int i = 0; i < 8; ++i) o[i] = (f16)0.0f;
    }
    *(f16x8*)(xq + (size_t)row * K_DIM + c8 * 8) = o;
}

__global__ __launch_bounds__(256) void quant_w_kernel(const float* __restrict__ w,
                                                      f16* __restrict__ wq,
                                                      float* __restrict__ scale_out) {
    int t = blockIdx.x * blockDim.x + threadIdx.x;
    int row = t / 160;
    int c8  = t % 160;
    const float* p = w + (size_t)row * K_DIM + c8 * 8;
    float v[8];
    *(float4*)&v[0] = *(const float4*)p;
    *(float4*)&v[4] = *(const float4*)(p + 4);
    float am = 0.0f;
    #pragma unroll
    for (int i = 0; i < 8; ++i) am = fmaxf(am, fabsf(v[i]));
    am = fmaxf(am, __shfl_xor(am, 1));
    am = fmaxf(am, __shfl_xor(am, 2));
    float scale = fmaxf(am / 6.0f, 1e-12f);
    if ((t & 3) == 0) scale_out[row * KB + (c8 >> 2)] = scale;
    f16x8 o;
    #pragma unroll
    for (int i = 0; i < 8; ++i) {
        float tq = v[i] / scale;
        float q  = copysignf(e2m1_level(fabsf(tq)), tq) * scale;
        o[i] = (f16)q;
    }
    *(f16x8*)(wq + (size_t)row * K_DIM + c8 * 8) = o;
}

// ---- GEMM 256x256, BK=64, 8 waves 2x4, per-wave 128x64 out ----
// LDS per tile-buffer: A [256 rows][8 chunks of 16B] (32KB) + B same; chunk c of row r
// at slot (c ^ (r&7)); stage pre-swizzles the global source chunk. 128 KiB total.

__device__ __forceinline__ void stage_half(const f16* __restrict__ g, f16* l, int tid) {
    #pragma unroll
    for (int s = 0; s < 2; ++s) {
        int j = s * 512 + tid;          // chunk 0..1023 (128 rows x 8 chunks)
        int r = j >> 3;
        int c = (j & 7) ^ (r & 7);
        GLDS(g + (size_t)r * K_DIM + c * 8, l + (size_t)j * 8);
    }
}

#define READ_A(dst, buf, rbase)                                                \
    _Pragma("unroll")                                                          \
    for (int fm = 0; fm < 4; ++fm) {                                           \
        dst[fm][0] = *(const f16x8*)&(buf)[((rbase) + fm * 16) * 64 + swz[0]]; \
        dst[fm][1] = *(const f16x8*)&(buf)[((rbase) + fm * 16) * 64 + swz[1]]; \
    }
#define READ_B(dst, buf, rbase)                                                \
    _Pragma("unroll")                                                          \
    for (int fn = 0; fn < 2; ++fn) {                                           \
        dst[fn][0] = *(const f16x8*)&(buf)[((rbase) + fn * 16) * 64 + swz[0]]; \
        dst[fn][1] = *(const f16x8*)&(buf)[((rbase) + fn * 16) * 64 + swz[1]]; \
    }
#define MFMA_Q(ma, mb, mo, no)                                                 \
    __builtin_amdgcn_s_setprio(1);                                             \
    _Pragma("unroll")                                                          \
    for (int fm = 0; fm < 4; ++fm)                                             \
        _Pragma("unroll")                                                      \
        for (int fn = 0; fn < 2; ++fn) {                                       \
            acc[fm + mo][fn + no] = __builtin_amdgcn_mfma_f32_16x16x32_f16(    \
                ma[fm][0], mb[fn][0], acc[fm + mo][fn + no], 0, 0, 0);         \
            acc[fm + mo][fn + no] = __builtin_amdgcn_mfma_f32_16x16x32_f16(    \
                ma[fm][1], mb[fn][1], acc[fm + mo][fn + no], 0, 0, 0);         \
        }                                                                      \
    __builtin_amdgcn_s_setprio(0);

// One K64-tile. X = buf[PAR] (tile t, restage target t+2), Y = other buf (tile t+1).
// aLO preloaded (read at Phi4 of tile t-1). VM: 4 steady, 0 at t=18, -1 at t=19.
template<int PAR, bool STAGE, int VM, bool READNEXT>
__device__ __forceinline__ void ktile(f16* Xa, f16* Xb, const f16* Ya,
                                      const f16* gA2, const f16* gB2,
                                      f16x8 (&aLO)[4][2],
                                      f32x4 (&acc)[8][4],
                                      int tid, int arow0, int brow0, const int (&swz)[2]) {
    f16x8 bLO[2][2], bHI[2][2], aHI[4][2];

    // ---- Phi1: read bLO+bHI (8); Q1 = aLO*bLO (bLO same-phase drain, aLO resident)
    READ_B(bLO, Xb, brow0);
    READ_B(bHI, Xb, brow0 + 32);
    MFMA_Q(aLO, bLO, 0, 0);

    // ---- Phi2: read aHI.k0 (4, consumed Phi3); Q2 = aLO*bHI; BAR (B-reads complete)
    #pragma unroll
    for (int fm = 0; fm < 4; ++fm)
        aHI[fm][0] = *(const f16x8*)&Xa[(arow0 + 64 + fm * 16) * 64 + swz[0]];
    MFMA_Q(aLO, bHI, 0, 2);
    BAR();

    // ---- Phi3: stage B(t+2) -> Xb; read aHI.k1 (4); Q3 = aHI*bHI (k0 cluster first,
    //      hiding k1 reads); then vmcnt(4) publishes tile t+1; BAR (A-reads complete)
    if (STAGE) { stage_half(gB2, Xb, tid); stage_half(gB2 + 128 * K_DIM, Xb + 8192, tid); }
    #pragma unroll
    for (int fm = 0; fm < 4; ++fm)
        aHI[fm][1] = *(const f16x8*)&Xa[(arow0 + 64 + fm * 16) * 64 + swz[1]];
    __builtin_amdgcn_s_setprio(1);
    #pragma unroll
    for (int ks = 0; ks < 2; ++ks)
        #pragma unroll
        for (int fm = 0; fm < 4; ++fm)
            #pragma unroll
            for (int fn = 0; fn < 2; ++fn)
                acc[fm + 4][fn + 2] = __builtin_amdgcn_mfma_f32_16x16x32_f16(
                    aHI[fm][ks], bHI[fn][ks], acc[fm + 4][fn + 2], 0, 0, 0);
    __builtin_amdgcn_s_setprio(0);
    if (VM >= 0) { if (VM == 4) VMCNT(4); else VMCNT(0); }
    BAR();

    // ---- Phi4: stage A(t+2) -> Xa; read aLO(t+1) from Ya (published); Q4 = aHI*bLO.
    //      No trailing barrier: flows into next tile's Phi1.
    if (STAGE) { stage_half(gA2, Xa, tid); stage_half(gA2 + 128 * K_DIM, Xa + 8192, tid); }
    if (READNEXT) { READ_A(aLO, Ya, arow0); }
    MFMA_Q(aHI, bLO, 4, 0);
}

__global__ __launch_bounds__(512, 2) void gemm_kernel(const f16* __restrict__ A,
                                                      const f16* __restrict__ B,
                                                      const float* __restrict__ bias,
                                                      float* __restrict__ C) {
    extern __shared__ f16 sm[];            // 2 tile-bufs x (A 16384 + B 16384 f16) = 128 KiB
    int mt = blockIdx.x / NTN;
    int nt = blockIdx.x % NTN;

    int tid  = threadIdx.x;
    int lane = tid & 63;
    int wid  = tid >> 6;
    int wr   = wid >> 2;                   // 0..1
    int wc   = wid & 3;                    // 0..3
    int l15  = lane & 15;

    int swz[2] = { (((lane >> 4)    ) ^ (lane & 7)) * 8,
                   (((lane >> 4) + 4) ^ (lane & 7)) * 8 };
    int arow0 = wr * 128 + l15;
    int brow0 = wc * 64 + l15;

    const f16* gAb = A + (size_t)(mt * 256) * K_DIM;
    const f16* gBb = B + (size_t)(nt * 256) * K_DIM;

    f16* A0 = sm;
    f16* B0 = sm + 16384;
    f16* A1 = sm + 32768;
    f16* B1 = sm + 49152;

    f32x4 acc[8][4] = {};
    f16x8 aLO[4][2];

    // prologue: stage tiles 0 and 1 fully (A0,B0,A1,B1 = 16 glds); vmcnt(8) publishes
    // tile0 (tile1's 8 stay in flight, drained by Phi3(0)'s vmcnt(4) chain); read aLO(0).
    stage_half(gAb,               A0,        tid);
    stage_half(gAb + 128 * K_DIM, A0 + 8192, tid);
    stage_half(gBb,               B0,        tid);
    stage_half(gBb + 128 * K_DIM, B0 + 8192, tid);
    stage_half(gAb + 64,               A1,        tid);
    stage_half(gAb + 64 + 128 * K_DIM, A1 + 8192, tid);
    stage_half(gBb + 64,               B1,        tid);
    stage_half(gBb + 64 + 128 * K_DIM, B1 + 8192, tid);
    VMCNT(8);
    BAR();
    READ_A(aLO, A0, arow0);

    // steady vmcnt(4) ledger at Phi3(t): queue = B(t+1),A(t+1),B(t+2) -> drain t+1.
    // (Phi3(0): queue = A1(4 of 8 prologue remain? no: prologue left A1+B1=8; B2 issued
    //  -> 12; vmcnt(4) drains A1,B1 ✓ same as steady.)
    for (int tt = 0; tt < 9; ++tt) {
        int t = 2 * tt;
        ktile<0, true, 4, true>(A0, B0, A1,
                                gAb + (t + 2) * 64, gBb + (t + 2) * 64,
                                aLO, acc, tid, arow0, brow0, swz);
        ktile<1, true, 4, true>(A1, B1, A0,
                                gAb + (t + 3) * 64, gBb + (t + 3) * 64,
                                aLO, acc, tid, arow0, brow0, swz);
    }
    ktile<0, false, 0, true>(A0, B0, A1, gAb, gBb,
                             aLO, acc, tid, arow0, brow0, swz);   // t=18
    ktile<1, false, -1, false>(A1, B1, A0, gAb, gBb,
                               aLO, acc, tid, arow0, brow0, swz); // t=19

    // ---- epilogue: C = acc + bias.  C/D layout: col=lane&15, row=(lane>>4)*4+j
    int crow0 = mt * 256 + wr * 128;
    int ccol  = nt * 256 + wc * 64 + l15;
    float bz[4];
    #pragma unroll
    for (int fn = 0; fn < 4; ++fn) bz[fn] = bias[ccol + fn * 16];

    #pragma unroll
    for (int fm = 0; fm < 8; ++fm) {
        #pragma unroll
        for (int j = 0; j < 4; ++j) {
            int row = crow0 + fm * 16 + (lane >> 4) * 4 + j;
            if (row < M_ROWS) {
                float* cp = C + (size_t)row * N_COLS + ccol;
                #pragma unroll
                for (int fn = 0; fn < 4; ++fn)
                    cp[fn * 16] = acc[fm][fn][j] + bz[fn];
            }
        }
    }
}

extern "C" void kernel_launch(void* const* d_in, const int* in_sizes, int n_in,
                              void* d_out, int out_size, void* d_ws, size_t ws_size,
                              hipStream_t stream) {
    const float* x      = (const float*)d_in[0];
    const float* weight = (const float*)d_in[1];
    const float* bias   = (const float*)d_in[2];
    float* out     = (float*)d_out;
    float* scale_w = (float*)d_out + (size_t)M_ROWS * N_COLS;

    f16* xq = (f16*)d_ws;
    f16* wq = (f16*)((char*)d_ws + (size_t)M_PAD * K_DIM * sizeof(f16));

    (void)hipFuncSetAttribute((const void*)gemm_kernel,
                              hipFuncAttributeMaxDynamicSharedMemorySize, 131072);

    {
        int threads = M_PAD * (K_DIM / 8);
        quant_x_kernel<<<threads / 256, 256, 0, stream>>>(x, xq);
    }
    {
        int threads = N_COLS * (K_DIM / 8);
        quant_w_kernel<<<threads / 256, 256, 0, stream>>>(weight, wq, scale_w);
    }
    {
        int grid = (M_PAD / 256) * (N_COLS / 256);   // 47 * 20 = 940
        gemm_kernel<<<grid, 512, 131072, stream>>>(xq, wq, bias, out);
    }
}